// Round 4
// baseline (627.777 us; speedup 1.0000x reference)
//
#include <hip/hip_runtime.h>
#include <stdint.h>

#define B_ 16
#define C_ 512
#define N_ 4096
#define K_ 64
#define NUM_STAGES 3

typedef __bf16 bf16x8 __attribute__((ext_vector_type(8)));
typedef float f32x4 __attribute__((ext_vector_type(4)));

__device__ __forceinline__ uint16_t f2bf(float x) {
  union { float f; uint32_t u; } v; v.f = x;
  uint32_t r = (v.u + 0x7FFFu + ((v.u >> 16) & 1u)) >> 16;
  return (uint16_t)r;
}

__device__ __forceinline__ void async16(const uint16_t* g, uint16_t* l) {
  __builtin_amdgcn_global_load_lds(
      (const __attribute__((address_space(1))) unsigned int*)g,
      (__attribute__((address_space(3))) unsigned int*)l, 16, 0, 0);
}

// ---------------- prep: fp32 feats -> bf16 f [B][C][N] and fT [B][N][C] ----
// 64c x 256n tile. All global streams >=512B contiguous per wave-instr.
__global__ __launch_bounds__(256) void k_prep(const float* __restrict__ feats,
                                              uint16_t* __restrict__ f16,
                                              uint16_t* __restrict__ fT16) {
  __shared__ uint16_t tile[64][264];  // pad 8 elem (16B) to spread gather banks
  int b = blockIdx.z, c0 = blockIdx.y * 64, n0 = blockIdx.x * 256;
  int t = threadIdx.x, w = t >> 6, lane = t & 63;
  const float* src = feats + ((size_t)b * C_ + c0) * N_ + n0;
  uint16_t* dst = f16 + ((size_t)b * C_ + c0) * N_ + n0;
  // each wave handles 16 c-rows; per row: 64 lanes x float4 = 1KB read
  for (int i = 0; i < 16; ++i) {
    int c = 4 * i + w;
    int n = lane * 4;
    float4 v = *(const float4*)(src + (size_t)c * N_ + n);
    ushort4 x;
    x.x = f2bf(v.x); x.y = f2bf(v.y); x.z = f2bf(v.z); x.w = f2bf(v.w);
    *(ushort4*)(dst + (size_t)c * N_ + n) = x;   // 512B/instr
    *(ushort4*)&tile[c][n] = x;
  }
  __syncthreads();
  // transpose out: per instr 8 n-rows x 128B = 1KB contiguous
  uint16_t* dstT = fT16 + ((size_t)b * N_ + n0) * C_ + c0;
  for (int j = 0; j < 8; ++j) {
    int n = w * 64 + j * 8 + (lane >> 3);
    int cb = (lane & 7) * 8;
    union { uint16_t u[8]; uint4 v; } y;
#pragma unroll
    for (int q = 0; q < 8; ++q) y.u[q] = tile[cb + q][n];
    *(uint4*)(dstT + (size_t)n * C_ + cb) = y.v;  // 16B/lane, 1KB/instr
  }
}

// ---------------- init: l2norm(bases over C) -> basis [B][C][K], basisT [B][K][C]
__global__ __launch_bounds__(256) void k_init_basis(const float* __restrict__ bases,
                                                    uint16_t* __restrict__ basis,
                                                    uint16_t* __restrict__ basisT) {
  int b = blockIdx.x;
  int t = threadIdx.x;
  __shared__ float red[256];
  __shared__ float inv[64];
  int k = t & 63;
  float s = 0.f;
  for (int c = (t >> 6); c < C_; c += 4) {
    float v = bases[c * K_ + k];
    s += v * v;
  }
  red[t] = s;
  __syncthreads();
  if (t < 64) {
    float tot = red[t] + red[t + 64] + red[t + 128] + red[t + 192];
    inv[t] = 1.f / (1e-6f + sqrtf(tot));
  }
  __syncthreads();
  uint16_t* ob = basis + (size_t)b * C_ * K_;
  for (int i = 0; i < (C_ * K_) / 256; ++i) {
    int idx = t + 256 * i;
    int kk = idx & 63;
    ob[idx] = f2bf(bases[idx] * inv[kk]);
  }
  uint16_t* obT = basisT + (size_t)b * K_ * C_;
  for (int i = 0; i < (C_ * K_) / 256; ++i) {
    int idx = t + 256 * i;
    int kk = idx >> 9;
    int cc = idx & 511;
    obT[idx] = f2bf(bases[cc * K_ + kk] * inv[kk]);
  }
}

// ---------------- GEMM1 + fused softmax: attn[n,k] = softmax_k(sum_c fT[n,c]*basisT[k,c])
// 64n x 64k tile, c-steps of 128, 32KB LDS -> ~5 blocks/CU for cross-block overlap.
__global__ __launch_bounds__(256) void k_gemm1(const uint16_t* __restrict__ fT,
                                               const uint16_t* __restrict__ basisT,
                                               uint16_t* __restrict__ attn,    // [B][N][K]
                                               uint16_t* __restrict__ attnT,   // [B][K][N]
                                               int write_attn) {
  __shared__ __attribute__((aligned(16))) uint16_t ldsA[64 * 128]; // 16 KB
  __shared__ __attribute__((aligned(16))) uint16_t ldsB[64 * 128]; // 16 KB
  int b = blockIdx.y;
  int n0 = blockIdx.x * 64;
  int t = threadIdx.x;
  int w = t >> 6, lane = t & 63, l15 = lane & 15, quad = lane >> 4;
  const uint16_t* A = fT + ((size_t)b * N_ + n0) * C_;
  const uint16_t* Bm = basisT + (size_t)b * K_ * C_;
  f32x4 acc[4] = {};
  for (int cs = 0; cs < C_; cs += 128) {
    __syncthreads();
#pragma unroll
    for (int i = 0; i < 4; ++i) {
      int e = i * 256 + t;
      int row = e >> 4, ch = e & 15, sch = (ch + row) & 15;
      async16(A + (size_t)row * C_ + cs + sch * 8, ldsA + (i * 256 + (t & 192)) * 8);
    }
#pragma unroll
    for (int i = 0; i < 4; ++i) {
      int e = i * 256 + t;
      int row = e >> 4, ch = e & 15, sch = (ch + row) & 15;
      async16(Bm + (size_t)row * C_ + cs + sch * 8, ldsB + (i * 256 + (t & 192)) * 8);
    }
    __syncthreads();
#pragma unroll
    for (int s = 0; s < 4; ++s) {
      int g = s * 4 + quad;
      int ra = 16 * w + l15;
      bf16x8 af = *(const bf16x8*)(ldsA + (ra * 16 + ((g - ra) & 15)) * 8);
#pragma unroll
      for (int kt = 0; kt < 4; ++kt) {
        int rb = 16 * kt + l15;
        bf16x8 bv = *(const bf16x8*)(ldsB + (rb * 16 + ((g - rb) & 15)) * 8);
        acc[kt] = __builtin_amdgcn_mfma_f32_16x16x32_bf16(af, bv, acc[kt], 0, 0, 0);
      }
    }
  }
  // softmax over k=64; n = n0 + 16w + quad*4 + r, k = 16kt + l15
  float p[4][4];
#pragma unroll
  for (int r = 0; r < 4; ++r) {
    float m = fmaxf(fmaxf(acc[0][r], acc[1][r]), fmaxf(acc[2][r], acc[3][r]));
    m = fmaxf(m, __shfl_xor(m, 1));
    m = fmaxf(m, __shfl_xor(m, 2));
    m = fmaxf(m, __shfl_xor(m, 4));
    m = fmaxf(m, __shfl_xor(m, 8));
    float s = 0.f;
#pragma unroll
    for (int kt = 0; kt < 4; ++kt) { p[kt][r] = __expf(acc[kt][r] - m); s += p[kt][r]; }
    s += __shfl_xor(s, 1); s += __shfl_xor(s, 2);
    s += __shfl_xor(s, 4); s += __shfl_xor(s, 8);
    float inv = 1.f / s;
#pragma unroll
    for (int kt = 0; kt < 4; ++kt) p[kt][r] *= inv;
  }
  if (write_attn) {
    uint16_t* oa = attn + ((size_t)b * N_ + n0 + 16 * w + quad * 4) * K_;
#pragma unroll
    for (int r = 0; r < 4; ++r) {
#pragma unroll
      for (int kt = 0; kt < 4; ++kt) oa[(size_t)r * K_ + 16 * kt + l15] = f2bf(p[kt][r]);
    }
  }
#pragma unroll
  for (int kt = 0; kt < 4; ++kt) {
    ushort4 y;
    y.x = f2bf(p[kt][0]); y.y = f2bf(p[kt][1]);
    y.z = f2bf(p[kt][2]); y.w = f2bf(p[kt][3]);
    *(ushort4*)(attnT + ((size_t)b * K_ + 16 * kt + l15) * N_ + n0 + 16 * w + quad * 4) = y;
  }
}

// ---------------- GEMM2 (split-K=8): braw[s][b][c][k] = sum_{n in slice} attnT[k,n]*f[c,n]
// 64k x 64c tile, n-steps of 128, LDS-transposed epilogue -> [c][k] float4 stores.
__global__ __launch_bounds__(256) void k_gemm2(const uint16_t* __restrict__ f16,
                                               const uint16_t* __restrict__ attnT,
                                               float* __restrict__ braw) {
  extern __shared__ __attribute__((aligned(16))) uint16_t lds[]; // 32 KB
  uint16_t* ldsP = lds;              // 64 k-rows x 128 n
  uint16_t* ldsF = lds + 64 * 128;   // 64 c-rows x 128 n
  int b = blockIdx.z;
  int slice = blockIdx.y;
  int c0 = blockIdx.x * 64;
  int ns0 = slice * 512;
  int t = threadIdx.x;
  int w = t >> 6, lane = t & 63, l15 = lane & 15, quad = lane >> 4;
  const uint16_t* F = f16 + ((size_t)b * C_ + c0) * N_;
  const uint16_t* P = attnT + (size_t)b * K_ * N_;
  f32x4 acc[4] = {};
  for (int ns = ns0; ns < ns0 + 512; ns += 128) {
    __syncthreads();
#pragma unroll
    for (int i = 0; i < 4; ++i) {
      int e = i * 256 + t;
      int row = e >> 4, ch = e & 15, sch = (ch + row) & 15;
      async16(P + (size_t)row * N_ + ns + sch * 8, ldsP + (i * 256 + (t & 192)) * 8);
    }
#pragma unroll
    for (int i = 0; i < 4; ++i) {
      int e = i * 256 + t;
      int row = e >> 4, ch = e & 15, sch = (ch + row) & 15;
      async16(F + (size_t)row * N_ + ns + sch * 8, ldsF + (i * 256 + (t & 192)) * 8);
    }
    __syncthreads();
#pragma unroll
    for (int s = 0; s < 4; ++s) {
      int g = s * 4 + quad;
      int rc = 16 * w + l15;
      bf16x8 fv = *(const bf16x8*)(ldsF + (rc * 16 + ((g - rc) & 15)) * 8);
#pragma unroll
      for (int kt = 0; kt < 4; ++kt) {
        int rk = 16 * kt + l15;
        bf16x8 av = *(const bf16x8*)(ldsP + (rk * 16 + ((g - rk) & 15)) * 8);
        acc[kt] = __builtin_amdgcn_mfma_f32_16x16x32_bf16(av, fv, acc[kt], 0, 0, 0);
      }
    }
  }
  // D[k][c]: k = 16kt + quad*4 + r, c = c0 + 16w + l15. Transpose to [c][k] in LDS.
  __syncthreads();
  float* ldsT = (float*)lds;  // 64 c x 68 k-words = 17.4 KB
#pragma unroll
  for (int kt = 0; kt < 4; ++kt) {
    float4 v = make_float4(acc[kt][0], acc[kt][1], acc[kt][2], acc[kt][3]);
    *(float4*)(ldsT + (16 * w + l15) * 68 + 16 * kt + quad * 4) = v;
  }
  __syncthreads();
  float* outp = braw + (((size_t)slice * B_ + b) * C_ + c0) * K_;
#pragma unroll
  for (int it = 0; it < 4; ++it) {
    int c = (t >> 4) + 16 * it;
    int k = (t & 15) * 4;
    float4 v = *(const float4*)(ldsT + c * 68 + k);
    *(float4*)(outp + (size_t)c * K_ + k) = v;  // 256B/row segments
  }
}

// ---------------- l2norm over C, sum 8 slices; basis [B][C][K] + basisT [B][K][C]
__global__ __launch_bounds__(1024) void k_l2norm(const float* __restrict__ braw,
                                                 uint16_t* __restrict__ basisT,
                                                 uint16_t* __restrict__ basis) {
  int b = blockIdx.x;
  int t = threadIdx.x, w = t >> 6, lane = t & 63;
  __shared__ float red[16][64];
  __shared__ float invs[64];
  float ss = 0.f;
  for (int c = w; c < C_; c += 16) {
    float v = 0.f;
#pragma unroll
    for (int s = 0; s < 8; ++s)
      v += braw[(((size_t)s * B_ + b) * C_ + c) * K_ + lane];
    ss += v * v;
  }
  red[w][lane] = ss;
  __syncthreads();
  if (t < 64) {
    float tot = 0.f;
#pragma unroll
    for (int j = 0; j < 16; ++j) tot += red[j][t];
    invs[t] = 1.f / (1e-6f + sqrtf(tot));
  }
  __syncthreads();
  float inv = invs[lane];
  for (int c = w; c < C_; c += 16) {
    float v = 0.f;
#pragma unroll
    for (int s = 0; s < 8; ++s)
      v += braw[(((size_t)s * B_ + b) * C_ + c) * K_ + lane];
    uint16_t y = f2bf(v * inv);
    basis[((size_t)b * C_ + c) * K_ + lane] = y;   // 128B/instr
    basisT[((size_t)b * K_ + lane) * C_ + c] = y;  // scatter, 1MB total
  }
}

// ---------------- recon: out[b,c,n] = sum_k basis[c,k]*attn[n,k] (fp32)
// 256n x 64c per block; LDS-transposed epilogue -> 1KB row stores.
__global__ __launch_bounds__(256) void k_recon(const uint16_t* __restrict__ attn,
                                               const uint16_t* __restrict__ basis,
                                               float* __restrict__ out) {
  extern __shared__ __attribute__((aligned(16))) uint16_t lds[];
  uint16_t* ldsA = lds;              // 256 n-rows x 64 k = 32 KB
  uint16_t* ldsB = lds + 256 * 64;   // 64 c-rows x 64 k = 8 KB
  int b = blockIdx.z, c0 = blockIdx.y * 64, n0 = blockIdx.x * 256;
  int t = threadIdx.x, w = t >> 6, lane = t & 63, l15 = lane & 15, quad = lane >> 4;
  const uint16_t* A = attn + ((size_t)b * N_ + n0) * K_;
  const uint16_t* Bm = basis + ((size_t)b * C_ + c0) * K_;
#pragma unroll
  for (int i = 0; i < 8; ++i) {
    int e = i * 256 + t;
    int row = e >> 3, ch = e & 7, sch = (ch + row) & 7;
    async16(A + (size_t)row * K_ + sch * 8, ldsA + (i * 256 + (t & 192)) * 8);
  }
#pragma unroll
  for (int i = 0; i < 2; ++i) {
    int e = i * 256 + t;
    int row = e >> 3, ch = e & 7, sch = (ch + row) & 7;
    async16(Bm + (size_t)row * K_ + sch * 8, ldsB + (i * 256 + (t & 192)) * 8);
  }
  f32x4 acc[4][4] = {};  // [mt][kt]: n = 64w+16mt+quad*4+r, c = 16kt+l15
  __syncthreads();
#pragma unroll
  for (int s = 0; s < 2; ++s) {
    int g = s * 4 + quad;
    bf16x8 bv[4];
#pragma unroll
    for (int kt = 0; kt < 4; ++kt) {
      int rb = 16 * kt + l15;
      bv[kt] = *(const bf16x8*)(ldsB + (rb * 8 + ((g - rb) & 7)) * 8);
    }
#pragma unroll
    for (int mt = 0; mt < 4; ++mt) {
      int ra = 64 * w + 16 * mt + l15;
      bf16x8 af = *(const bf16x8*)(ldsA + (ra * 8 + ((g - ra) & 7)) * 8);
#pragma unroll
      for (int kt = 0; kt < 4; ++kt)
        acc[mt][kt] = __builtin_amdgcn_mfma_f32_16x16x32_bf16(af, bv[kt], acc[mt][kt], 0, 0, 0);
    }
  }
  __syncthreads();
  float* ldsT = (float*)lds;  // 64 c x 260 n-words = 66.6 KB
#pragma unroll
  for (int mt = 0; mt < 4; ++mt) {
#pragma unroll
    for (int kt = 0; kt < 4; ++kt) {
      float4 v = make_float4(acc[mt][kt][0], acc[mt][kt][1], acc[mt][kt][2], acc[mt][kt][3]);
      *(float4*)(ldsT + (16 * kt + l15) * 260 + 64 * w + 16 * mt + quad * 4) = v;
    }
  }
  __syncthreads();
  float* op = out + ((size_t)b * C_ + c0) * N_ + n0;
#pragma unroll
  for (int it = 0; it < 16; ++it) {
    int c = (t >> 6) + 4 * it;
    float4 v = *(const float4*)(ldsT + c * 260 + lane * 4);
    *(float4*)(op + (size_t)c * N_ + lane * 4) = v;  // 1KB/instr per row
  }
}

extern "C" void kernel_launch(void* const* d_in, const int* in_sizes, int n_in,
                              void* d_out, int out_size, void* d_ws, size_t ws_size,
                              hipStream_t stream) {
  const float* feats = (const float*)d_in[0];
  const float* bases = (const float*)d_in[1];
  float* out = (float*)d_out;
  char* ws = (char*)d_ws;
  uint16_t* f16 = (uint16_t*)(ws);                         // 64 MB
  uint16_t* fT16 = (uint16_t*)(ws + 67108864);             // 64 MB
  uint16_t* attn = (uint16_t*)(ws + 134217728);            // 8 MB
  uint16_t* attnT = (uint16_t*)(ws + 142606336);           // 8 MB
  uint16_t* basis = (uint16_t*)(ws + 150994944);           // 1 MB
  uint16_t* basisT = (uint16_t*)(ws + 152043520);          // 1 MB
  float* braw = (float*)(ws + 153092096);                  // 16.8 MB (8 slices)

  const int ldsG2 = 64 * 128 * 2 * 2;                 // 32 KB
  const int ldsRe = 64 * 260 * 4;                     // 66.6 KB (>= staging 40 KB)
  (void)hipFuncSetAttribute((const void*)k_gemm2,
                            hipFuncAttributeMaxDynamicSharedMemorySize, ldsG2);
  (void)hipFuncSetAttribute((const void*)k_recon,
                            hipFuncAttributeMaxDynamicSharedMemorySize, ldsRe);

  k_prep<<<dim3(16, 8, 16), 256, 0, stream>>>(feats, f16, fT16);
  k_init_basis<<<16, 256, 0, stream>>>(bases, basis, basisT);
  for (int st = 0; st < NUM_STAGES; ++st) {
    k_gemm1<<<dim3(64, 16), 256, 0, stream>>>(fT16, basisT, attn, attnT,
                                              st == NUM_STAGES - 1 ? 1 : 0);
    k_gemm2<<<dim3(8, 8, 16), 256, ldsG2, stream>>>(f16, attnT, braw);
    k_l2norm<<<16, 1024, 0, stream>>>(braw, basisT, basis);
  }
  k_recon<<<dim3(16, 8, 16), 256, ldsRe, stream>>>(attn, basis, out);
}

// Round 5
// 448.355 us; speedup vs baseline: 1.4002x; 1.4002x over previous
//
#include <hip/hip_runtime.h>
#include <stdint.h>

#define B_ 16
#define C_ 512
#define N_ 4096
#define K_ 64
#define NUM_STAGES 3

typedef __bf16 bf16x8 __attribute__((ext_vector_type(8)));
typedef float f32x4 __attribute__((ext_vector_type(4)));

__device__ __forceinline__ uint16_t f2bf(float x) {
  union { float f; uint32_t u; } v; v.f = x;
  uint32_t r = (v.u + 0x7FFFu + ((v.u >> 16) & 1u)) >> 16;
  return (uint16_t)r;
}

__device__ __forceinline__ void async16(const uint16_t* g, uint16_t* l) {
  __builtin_amdgcn_global_load_lds(
      (const __attribute__((address_space(1))) unsigned int*)g,
      (__attribute__((address_space(3))) unsigned int*)l, 16, 0, 0);
}

// ---------------- prep: fp32 feats -> bf16 f [B][C][N] and fT [B][N][C] ----
// (round-0 exact: measured 81us, 0 bank conflicts)
__global__ __launch_bounds__(256) void k_prep(const float* __restrict__ feats,
                                              uint16_t* __restrict__ f16,
                                              uint16_t* __restrict__ fT16) {
  __shared__ uint16_t tile[64][65];
  int b = blockIdx.z, c0 = blockIdx.y * 64, n0 = blockIdx.x * 64;
  int t = threadIdx.x;
  const float* src = feats + ((size_t)b * C_ + c0) * N_ + n0;
  uint16_t* dst = f16 + ((size_t)b * C_ + c0) * N_ + n0;
  int cl = t >> 4;          // 0..15
  int nl = (t & 15) * 4;    // 0..60
#pragma unroll
  for (int i = 0; i < 4; ++i) {
    int c = cl + 16 * i;
    float4 v = *(const float4*)(src + (size_t)c * N_ + nl);
    ushort4 x;
    x.x = f2bf(v.x); x.y = f2bf(v.y); x.z = f2bf(v.z); x.w = f2bf(v.w);
    *(ushort4*)(dst + (size_t)c * N_ + nl) = x;
    tile[c][nl + 0] = x.x; tile[c][nl + 1] = x.y;
    tile[c][nl + 2] = x.z; tile[c][nl + 3] = x.w;
  }
  __syncthreads();
  uint16_t* dstT = fT16 + ((size_t)b * N_ + n0) * C_ + c0;
#pragma unroll
  for (int i = 0; i < 4; ++i) {
    int n = cl + 16 * i;
    int c = nl;
    ushort4 y;
    y.x = tile[c + 0][n]; y.y = tile[c + 1][n];
    y.z = tile[c + 2][n]; y.w = tile[c + 3][n];
    *(ushort4*)(dstT + (size_t)n * C_ + c) = y;
  }
}

// ---------------- init: l2norm(bases over C) -> basis [B][C][K], basisT [B][K][C]
__global__ __launch_bounds__(256) void k_init_basis(const float* __restrict__ bases,
                                                    uint16_t* __restrict__ basis,
                                                    uint16_t* __restrict__ basisT) {
  int b = blockIdx.x;
  int t = threadIdx.x;
  __shared__ float red[256];
  __shared__ float inv[64];
  int k = t & 63;
  float s = 0.f;
  for (int c = (t >> 6); c < C_; c += 4) {
    float v = bases[c * K_ + k];
    s += v * v;
  }
  red[t] = s;
  __syncthreads();
  if (t < 64) {
    float tot = red[t] + red[t + 64] + red[t + 128] + red[t + 192];
    inv[t] = 1.f / (1e-6f + sqrtf(tot));
  }
  __syncthreads();
  uint16_t* ob = basis + (size_t)b * C_ * K_;
  for (int i = 0; i < (C_ * K_) / 256; ++i) {
    int idx = t + 256 * i;
    int kk = idx & 63;
    ob[idx] = f2bf(bases[idx] * inv[kk]);
  }
  uint16_t* obT = basisT + (size_t)b * K_ * C_;
  for (int i = 0; i < (C_ * K_) / 256; ++i) {
    int idx = t + 256 * i;
    int kk = idx >> 9;
    int cc = idx & 511;
    obT[idx] = f2bf(bases[cc * K_ + kk] * inv[kk]);
  }
}

// ---------------- GEMM1 + fused softmax (round-0 exact config)
__global__ __launch_bounds__(256) void k_gemm1(const uint16_t* __restrict__ fT,
                                               const uint16_t* __restrict__ basisT,
                                               uint16_t* __restrict__ attn,    // [B][N][K]
                                               uint16_t* __restrict__ attnT,   // [B][K][N]
                                               int write_attn) {
  __shared__ __attribute__((aligned(16))) uint16_t ldsA[64 * 64];
  __shared__ __attribute__((aligned(16))) uint16_t ldsB[64 * 64];
  int b = blockIdx.y;
  int n0 = blockIdx.x * 64;
  int t = threadIdx.x;
  int w = t >> 6, lane = t & 63, l15 = lane & 15, quad = lane >> 4;
  const uint16_t* A = fT + ((size_t)b * N_ + n0) * C_;
  const uint16_t* Bm = basisT + (size_t)b * K_ * C_;
  f32x4 acc[4] = {};
  for (int cs = 0; cs < C_; cs += 64) {
    __syncthreads();
#pragma unroll
    for (int r = 0; r < 2; ++r) {
      int e = r * 256 + t;
      int row = e >> 3, ch = e & 7;
      int sch = (ch + row) & 7;
      async16(A + (size_t)row * C_ + cs + sch * 8, ldsA + (r * 256 + (t & 192)) * 8);
    }
#pragma unroll
    for (int r = 0; r < 2; ++r) {
      int e = r * 256 + t;
      int row = e >> 3, ch = e & 7;
      int sch = (ch + row) & 7;
      async16(Bm + (size_t)row * C_ + cs + sch * 8, ldsB + (r * 256 + (t & 192)) * 8);
    }
    __syncthreads();
#pragma unroll
    for (int s = 0; s < 2; ++s) {
      int cc = s * 4 + quad;
      int ra = 16 * w + l15;
      bf16x8 af = *(const bf16x8*)(ldsA + (ra * 8 + ((cc - ra) & 7)) * 8);
#pragma unroll
      for (int t4 = 0; t4 < 4; ++t4) {
        int rb = 16 * t4 + l15;
        bf16x8 bv = *(const bf16x8*)(ldsB + (rb * 8 + ((cc - rb) & 7)) * 8);
        acc[t4] = __builtin_amdgcn_mfma_f32_16x16x32_bf16(af, bv, acc[t4], 0, 0, 0);
      }
    }
  }
  float p[4][4];
#pragma unroll
  for (int r = 0; r < 4; ++r) {
    float m = fmaxf(fmaxf(acc[0][r], acc[1][r]), fmaxf(acc[2][r], acc[3][r]));
    m = fmaxf(m, __shfl_xor(m, 1));
    m = fmaxf(m, __shfl_xor(m, 2));
    m = fmaxf(m, __shfl_xor(m, 4));
    m = fmaxf(m, __shfl_xor(m, 8));
    float s = 0.f;
#pragma unroll
    for (int t4 = 0; t4 < 4; ++t4) { p[t4][r] = __expf(acc[t4][r] - m); s += p[t4][r]; }
    s += __shfl_xor(s, 1); s += __shfl_xor(s, 2);
    s += __shfl_xor(s, 4); s += __shfl_xor(s, 8);
    float inv = 1.f / s;
#pragma unroll
    for (int t4 = 0; t4 < 4; ++t4) p[t4][r] *= inv;
  }
  if (write_attn) {
    uint16_t* oa = attn + ((size_t)b * N_ + n0 + 16 * w + quad * 4) * K_;
#pragma unroll
    for (int r = 0; r < 4; ++r) {
#pragma unroll
      for (int t4 = 0; t4 < 4; ++t4) oa[(size_t)r * K_ + 16 * t4 + l15] = f2bf(p[t4][r]);
    }
  }
#pragma unroll
  for (int t4 = 0; t4 < 4; ++t4) {
    ushort4 y;
    y.x = f2bf(p[t4][0]); y.y = f2bf(p[t4][1]);
    y.z = f2bf(p[t4][2]); y.w = f2bf(p[t4][3]);
    *(ushort4*)(attnT + ((size_t)b * K_ + 16 * t4 + l15) * N_ + n0 + 16 * w + quad * 4) = y;
  }
}

// ---------------- GEMM2 (round-0 exact): brawT[s][b][k][c], split-K=4
__global__ __launch_bounds__(256) void k_gemm2(const uint16_t* __restrict__ f16,
                                               const uint16_t* __restrict__ attnT,
                                               float* __restrict__ brawT) {
  __shared__ __attribute__((aligned(16))) uint16_t ldsA[32 * 64];
  __shared__ __attribute__((aligned(16))) uint16_t ldsB[64 * 64];
  int b = blockIdx.z;
  int c0 = blockIdx.x * 32;
  int slice = blockIdx.y;
  int ns0 = slice * 1024;
  int t = threadIdx.x, w = t >> 6, lane = t & 63, l15 = lane & 15, quad = lane >> 4;
  int h = w >> 1, kh = w & 1;
  const uint16_t* A = f16 + ((size_t)b * C_ + c0) * N_;
  const uint16_t* Bm = attnT + (size_t)b * K_ * N_;
  f32x4 acc[2] = {};
  for (int ns = ns0; ns < ns0 + 1024; ns += 64) {
    __syncthreads();
    {
      int row = t >> 3, ch = t & 7;
      int sch = (ch + row) & 7;
      async16(A + (size_t)row * N_ + ns + sch * 8, ldsA + (t & 192) * 8);
    }
#pragma unroll
    for (int r = 0; r < 2; ++r) {
      int e = r * 256 + t;
      int row = e >> 3, ch = e & 7;
      int sch = (ch + row) & 7;
      async16(Bm + (size_t)row * N_ + ns + sch * 8, ldsB + (r * 256 + (t & 192)) * 8);
    }
    __syncthreads();
#pragma unroll
    for (int s = 0; s < 2; ++s) {
      int cc = s * 4 + quad;
      int ra = 16 * h + l15;
      bf16x8 af = *(const bf16x8*)(ldsA + (ra * 8 + ((cc - ra) & 7)) * 8);
#pragma unroll
      for (int t2 = 0; t2 < 2; ++t2) {
        int rb = 32 * kh + 16 * t2 + l15;
        bf16x8 bv = *(const bf16x8*)(ldsB + (rb * 8 + ((cc - rb) & 7)) * 8);
        acc[t2] = __builtin_amdgcn_mfma_f32_16x16x32_bf16(af, bv, acc[t2], 0, 0, 0);
      }
    }
  }
  float* out = brawT + ((size_t)slice * B_ + b) * K_ * C_;
#pragma unroll
  for (int t2 = 0; t2 < 2; ++t2) {
    int k = 32 * kh + 16 * t2 + l15;
    float4 v = make_float4(acc[t2][0], acc[t2][1], acc[t2][2], acc[t2][3]);
    *(float4*)(out + (size_t)k * C_ + c0 + 16 * h + quad * 4) = v;
  }
}

// ---------------- FUSED l2norm + transpose: 256 blocks (16b x 16kg), 4 k/block
// reads brawT [4][B][K][C] once; writes basisT [B][K][C] + basis [B][C][K]
__global__ __launch_bounds__(256) void k_l2fused(const float* __restrict__ brawT,
                                                 uint16_t* __restrict__ basisT,
                                                 uint16_t* __restrict__ basis) {
  __shared__ float red[4][128];
  __shared__ float invs[4];
  int b = blockIdx.x, kg = blockIdx.y;
  int t = threadIdx.x;
  int c4 = (t & 127) * 4;       // c chunk of 4
  int khalf = t >> 7;           // 0/1 -> k' = khalf*2 + i
  float4 bs[2];
  float pr[2];
#pragma unroll
  for (int i = 0; i < 2; ++i) {
    int k = kg * 4 + khalf * 2 + i;
    float4 a = make_float4(0.f, 0.f, 0.f, 0.f);
#pragma unroll
    for (int s = 0; s < 4; ++s) {
      const float* rp = brawT + (((size_t)s * B_ + b) * K_ + k) * C_ + c4;
      float4 v = *(const float4*)rp;
      a.x += v.x; a.y += v.y; a.z += v.z; a.w += v.w;
    }
    bs[i] = a;
    pr[i] = a.x * a.x + a.y * a.y + a.z * a.z + a.w * a.w;
  }
  red[khalf * 2 + 0][t & 127] = pr[0];
  red[khalf * 2 + 1][t & 127] = pr[1];
  __syncthreads();
  if (t < 4) {
    float s = 0.f;
#pragma unroll
    for (int j = 0; j < 128; ++j) s += red[t][j];
    invs[t] = 1.f / (1e-6f + sqrtf(s));
  }
  __syncthreads();
#pragma unroll
  for (int i = 0; i < 2; ++i) {
    int kk = khalf * 2 + i;
    int k = kg * 4 + kk;
    float inv = invs[kk];
    ushort4 y;
    y.x = f2bf(bs[i].x * inv); y.y = f2bf(bs[i].y * inv);
    y.z = f2bf(bs[i].z * inv); y.w = f2bf(bs[i].w * inv);
    *(ushort4*)(basisT + ((size_t)b * K_ + k) * C_ + c4) = y;
    uint16_t* ob = basis + (size_t)b * C_ * K_ + k;
    ob[(size_t)(c4 + 0) * K_] = y.x;
    ob[(size_t)(c4 + 1) * K_] = y.y;
    ob[(size_t)(c4 + 2) * K_] = y.z;
    ob[(size_t)(c4 + 3) * K_] = y.w;
  }
}

// ---------------- recon: out[b,c,n] = sum_k basis[c,k]*attn[n,k] (fp32)
// round-0 tile + LDS-transposed epilogue (256B segment stores)
__global__ __launch_bounds__(256) void k_recon(const uint16_t* __restrict__ attn,
                                               const uint16_t* __restrict__ basis,
                                               float* __restrict__ out) {
  __shared__ __attribute__((aligned(16))) char smem[64 * 68 * 4]; // 17.4 KB union
  uint16_t* ldsA = (uint16_t*)smem;              // 64 n x 64 k (8 KB)
  uint16_t* ldsB = (uint16_t*)(smem + 8192);     // 64 c x 64 k (8 KB)
  float* ldsT = (float*)smem;                    // 64 c x 68 n
  int b = blockIdx.z, c0 = blockIdx.y * 64, n0 = blockIdx.x * 64;
  int t = threadIdx.x, w = t >> 6, lane = t & 63, l15 = lane & 15, quad = lane >> 4;
  const uint16_t* A = attn + ((size_t)b * N_ + n0) * K_;
  const uint16_t* Bm = basis + ((size_t)b * C_ + c0) * K_;
#pragma unroll
  for (int r = 0; r < 2; ++r) {
    int e = r * 256 + t;
    int row = e >> 3, ch = e & 7, sch = (ch + row) & 7;
    async16(A + (size_t)row * K_ + sch * 8, ldsA + (r * 256 + (t & 192)) * 8);
  }
#pragma unroll
  for (int r = 0; r < 2; ++r) {
    int e = r * 256 + t;
    int row = e >> 3, ch = e & 7, sch = (ch + row) & 7;
    async16(Bm + (size_t)row * K_ + sch * 8, ldsB + (r * 256 + (t & 192)) * 8);
  }
  f32x4 acc[4] = {};
  __syncthreads();
#pragma unroll
  for (int s = 0; s < 2; ++s) {
    int cc = s * 4 + quad;
    int ra = 16 * w + l15;
    bf16x8 af = *(const bf16x8*)(ldsA + (ra * 8 + ((cc - ra) & 7)) * 8);
#pragma unroll
    for (int t4 = 0; t4 < 4; ++t4) {
      int rb = 16 * t4 + l15;
      bf16x8 bv = *(const bf16x8*)(ldsB + (rb * 8 + ((cc - rb) & 7)) * 8);
      acc[t4] = __builtin_amdgcn_mfma_f32_16x16x32_bf16(af, bv, acc[t4], 0, 0, 0);
    }
  }
  // transpose through LDS: acc holds D[n'][c'] with n'=16w+quad*4+r, c'=16t4+l15
  __syncthreads();
#pragma unroll
  for (int t4 = 0; t4 < 4; ++t4) {
    float4 v = make_float4(acc[t4][0], acc[t4][1], acc[t4][2], acc[t4][3]);
    *(float4*)(ldsT + (size_t)(16 * t4 + l15) * 68 + 16 * w + quad * 4) = v;
  }
  __syncthreads();
  float* op = out + ((size_t)b * C_ + c0) * N_ + n0;
#pragma unroll
  for (int j = 0; j < 16; ++j) {
    int c = 4 * j + w;
    op[(size_t)c * N_ + lane] = ldsT[(size_t)c * 68 + lane];  // 256B/row, 4 rows/instr
  }
}

extern "C" void kernel_launch(void* const* d_in, const int* in_sizes, int n_in,
                              void* d_out, int out_size, void* d_ws, size_t ws_size,
                              hipStream_t stream) {
  const float* feats = (const float*)d_in[0];
  const float* bases = (const float*)d_in[1];
  float* out = (float*)d_out;
  char* ws = (char*)d_ws;
  uint16_t* f16 = (uint16_t*)(ws);                         // 64 MB
  uint16_t* fT16 = (uint16_t*)(ws + 67108864);             // 64 MB
  uint16_t* attn = (uint16_t*)(ws + 134217728);            // 8 MB
  uint16_t* attnT = (uint16_t*)(ws + 142606336);           // 8 MB
  uint16_t* basis = (uint16_t*)(ws + 150994944);           // 1 MB
  uint16_t* basisT = (uint16_t*)(ws + 152043520);          // 1 MB
  float* brawT = (float*)(ws + 153092096);                 // 8 MB (4 slices)

  k_prep<<<dim3(64, 8, 16), 256, 0, stream>>>(feats, f16, fT16);
  k_init_basis<<<16, 256, 0, stream>>>(bases, basis, basisT);
  for (int st = 0; st < NUM_STAGES; ++st) {
    k_gemm1<<<dim3(64, 16), 256, 0, stream>>>(fT16, basisT, attn, attnT,
                                              st == NUM_STAGES - 1 ? 1 : 0);
    k_gemm2<<<dim3(16, 4, 16), 256, 0, stream>>>(f16, attnT, brawT);
    k_l2fused<<<dim3(16, 16), 256, 0, stream>>>(brawT, basisT, basis);
  }
  k_recon<<<dim3(64, 8, 16), 256, 0, stream>>>(attn, basis, out);
}